// Round 5
// baseline (305.398 us; speedup 1.0000x reference)
//
#include <hip/hip_runtime.h>

#define NN 50000
#define NE 800000
#define IN_C 256
#define HID_C 256
#define OUT_C 128

#define NBUCK 196   // ceil(NN/256) buckets of 256 nodes (by col)
#define CHUNK 4096  // edges per pass-A block
#define NPA 196     // ceil(NE/CHUNK)
#define CAP_B 5120  // pass-B LDS capacity (bucket mean 4096, sigma ~64)

typedef unsigned short u16;
typedef __attribute__((ext_vector_type(8))) short short8;
typedef __attribute__((ext_vector_type(8))) unsigned short ushort8;
typedef __attribute__((ext_vector_type(4))) float f32x4;

__device__ __forceinline__ u16 f2b(float f) {
  unsigned int u = __float_as_uint(f);
  return (u16)((u + 0x7FFFu + ((u >> 16) & 1u)) >> 16);  // RNE
}
__device__ __forceinline__ float b2f(u16 s) {
  return __uint_as_float(((unsigned int)s) << 16);
}

// ---------------- fused: weight convert+transpose, cnt zeroing, zero-row seed ----------------

__global__ __launch_bounds__(256) void convw_zero(const float* __restrict__ W1,
                                                  const float* __restrict__ W2,
                                                  u16* __restrict__ W1t,
                                                  u16* __restrict__ W2t,
                                                  int* __restrict__ cnt,
                                                  u16* __restrict__ Hbz,
                                                  u16* __restrict__ H3z,
                                                  int nzb) {
  int b = blockIdx.x;
  if (b < 256) {
    int id = b * 256 + threadIdx.x;
    if (id < 256 * 256) {
      int n = id >> 8, k = id & 255;
      W1t[id] = f2b(W1[k * 256 + n]);
    }
    if (id < 128 * 256) {
      int n = id >> 8, k = id & 255;
      W2t[id] = f2b(W2[k * 128 + n]);
    }
  } else if (b < 256 + nzb) {
    int i = (b - 256) * 256 + threadIdx.x;
    if (i < NN) cnt[i] = 0;
  } else {
    // zero rows used to absorb clamped tail gathers in the agg kernels
    if (threadIdx.x < 256) Hbz[threadIdx.x] = 0;
    if (threadIdx.x < 128) H3z[threadIdx.x] = 0;
  }
}

// ---------------- CSR build ----------------

__global__ __launch_bounds__(256) void hist_kernel(const int* __restrict__ col,
                                                   int* __restrict__ cnt, int E) {
  int e = blockIdx.x * blockDim.x + threadIdx.x;
  if (e < E) atomicAdd(&cnt[col[e]], 1);
}

__global__ __launch_bounds__(256) void scan1_kernel(const int* __restrict__ cnt,
                                                    int* __restrict__ bsum, int n) {
  __shared__ int ws[4];
  int i = blockIdx.x * 256 + threadIdx.x;
  int lane = threadIdx.x & 63, wid = threadIdx.x >> 6;
  int v = (i < n) ? cnt[i] : 0;
#pragma unroll
  for (int off = 32; off > 0; off >>= 1) v += __shfl_down(v, off, 64);
  if (lane == 0) ws[wid] = v;
  __syncthreads();
  if (threadIdx.x == 0) bsum[blockIdx.x] = ws[0] + ws[1] + ws[2] + ws[3];
}

__global__ __launch_bounds__(256) void scan2_kernel(const int* __restrict__ bsum,
                                                    int* __restrict__ boff,
                                                    int* __restrict__ row_off,
                                                    int nb, int n) {
  __shared__ int wsum[4], wpre[5];
  int lane = threadIdx.x & 63, wid = threadIdx.x >> 6;
  int v = (threadIdx.x < nb) ? bsum[threadIdx.x] : 0;
  int s = v;
#pragma unroll
  for (int off = 1; off < 64; off <<= 1) {
    int t = __shfl_up(s, off, 64);
    if (lane >= off) s += t;
  }
  if (lane == 63) wsum[wid] = s;
  __syncthreads();
  if (threadIdx.x == 0) {
    int acc = 0;
#pragma unroll
    for (int w = 0; w < 4; ++w) { wpre[w] = acc; acc += wsum[w]; }
    wpre[4] = acc;
  }
  __syncthreads();
  if (threadIdx.x < nb) boff[threadIdx.x] = wpre[wid] + (s - v);
  if (threadIdx.x == 0) row_off[n] = wpre[4];
}

// scan3 also seeds per-bucket stage cursors (bcur[b] = row_off[b*256])
__global__ __launch_bounds__(256) void scan3_kernel(const int* __restrict__ cnt,
                                                    const int* __restrict__ boff,
                                                    int* __restrict__ row_off,
                                                    int* __restrict__ bcur,
                                                    float* __restrict__ dinv, int n) {
  __shared__ int wsum[4], wpre[4];
  int i = blockIdx.x * 256 + threadIdx.x;
  int lane = threadIdx.x & 63, wid = threadIdx.x >> 6;
  int v = (i < n) ? cnt[i] : 0;
  int s = v;
#pragma unroll
  for (int off = 1; off < 64; off <<= 1) {
    int t = __shfl_up(s, off, 64);
    if (lane >= off) s += t;
  }
  if (lane == 63) wsum[wid] = s;
  __syncthreads();
  if (threadIdx.x == 0) {
    int acc = 0;
#pragma unroll
    for (int w = 0; w < 4; ++w) { wpre[w] = acc; acc += wsum[w]; }
  }
  __syncthreads();
  if (i < n) {
    int off = boff[blockIdx.x] + wpre[wid] + (s - v);
    row_off[i] = off;
    if ((i & 255) == 0) bcur[i >> 8] = off;
    dinv[i] = rsqrtf((float)(v + 1));
  }
}

// ---------------- MFMA GEMM body (shared by plain and fused kernels) ----------------

template <bool A_IS_F32>
__device__ __forceinline__ void gemm_body(const void* __restrict__ Ap,
                                          const u16* __restrict__ Bt,
                                          const float* __restrict__ dscale,
                                          u16* __restrict__ C, int M, int N,
                                          int bx, int by,
                                          u16 (&Asl)[2][5120], u16 (&Bsl)[2][5120]) {
  const int tid = threadIdx.x;
  const int row0 = by * 128;
  const int col0 = bx * 128;

  f32x4 acc[4][4] = {};

  const int seg = tid & 7;
  const int rb = tid >> 3;
  const int wave = tid >> 6, lane = tid & 63;
  const int wm = wave >> 1, wn = wave & 1;
  const int qr = lane & 15, quad = lane >> 4;

  float4 aF[4];
  ushort4 aU[4];
  ushort4 bR[4];

  auto load_tiles = [&](int k0) {
    if constexpr (A_IS_F32) {
      const float* A = (const float*)Ap;
#pragma unroll
      for (int i = 0; i < 4; ++i) {
        int gr = row0 + rb + i * 32;
        aF[i] = (gr < M) ? *(const float4*)&A[(size_t)gr * 256 + k0 + seg * 4]
                         : make_float4(0.f, 0.f, 0.f, 0.f);
      }
    } else {
      const u16* A = (const u16*)Ap;
#pragma unroll
      for (int i = 0; i < 4; ++i) {
        int gr = row0 + rb + i * 32;
        aU[i] = (gr < M) ? *(const ushort4*)&A[(size_t)gr * 256 + k0 + seg * 4]
                         : make_ushort4(0, 0, 0, 0);
      }
    }
#pragma unroll
    for (int i = 0; i < 4; ++i) {
      int n = rb + i * 32;
      bR[i] = *(const ushort4*)&Bt[(size_t)(col0 + n) * 256 + k0 + seg * 4];
    }
  };

  auto write_lds = [&](int buf) {
#pragma unroll
    for (int i = 0; i < 4; ++i) {
      int r = rb + i * 32;
      ushort4 u;
      if constexpr (A_IS_F32) {
        u.x = f2b(aF[i].x); u.y = f2b(aF[i].y);
        u.z = f2b(aF[i].z); u.w = f2b(aF[i].w);
      } else {
        u = aU[i];
      }
      *(ushort4*)&Asl[buf][r * 40 + seg * 4] = u;
      *(ushort4*)&Bsl[buf][r * 40 + seg * 4] = bR[i];
    }
  };

  load_tiles(0);
  write_lds(0);
  __syncthreads();

#pragma unroll
  for (int it = 0; it < 8; ++it) {
    const int cur = it & 1;
    if (it < 7) load_tiles((it + 1) * 32);

    short8 afr[4], bfr[4];
#pragma unroll
    for (int mt = 0; mt < 4; ++mt)
      afr[mt] = *(const short8*)&Asl[cur][(wm * 64 + mt * 16 + qr) * 40 + quad * 8];
#pragma unroll
    for (int nt = 0; nt < 4; ++nt)
      bfr[nt] = *(const short8*)&Bsl[cur][(wn * 64 + nt * 16 + qr) * 40 + quad * 8];
#pragma unroll
    for (int mt = 0; mt < 4; ++mt)
#pragma unroll
      for (int nt = 0; nt < 4; ++nt)
        acc[mt][nt] = __builtin_amdgcn_mfma_f32_16x16x32_bf16(afr[mt], bfr[nt], acc[mt][nt], 0, 0, 0);

    if (it < 7) {
      write_lds(1 - cur);
      __syncthreads();
    }
  }

#pragma unroll
  for (int mt = 0; mt < 4; ++mt) {
#pragma unroll
    for (int i = 0; i < 4; ++i) {
      int gr = row0 + wm * 64 + mt * 16 + quad * 4 + i;
      if (gr < M) {
        float sc = dscale[gr];
#pragma unroll
        for (int nt = 0; nt < 4; ++nt) {
          int gc = col0 + wn * 64 + nt * 16 + qr;
          C[(size_t)gr * N + gc] = f2b(acc[mt][nt][i] * sc);
        }
      }
    }
  }
}

// plain GEMM kernel (layer 2)
template <bool A_IS_F32>
__global__ __launch_bounds__(256) void gemm_mfma(const void* __restrict__ Ap,
                                                 const u16* __restrict__ Bt,
                                                 const float* __restrict__ dscale,
                                                 u16* __restrict__ C, int M, int N) {
  __shared__ u16 Asl[2][5120];
  __shared__ u16 Bsl[2][5120];
  gemm_body<A_IS_F32>(Ap, Bt, dscale, C, M, N, blockIdx.x, blockIdx.y, Asl, Bsl);
}

// fused: GEMM1 (blocks [0,ngb)) + pass-A bucket scatter (blocks [ngb, ngb+NPA))
__global__ __launch_bounds__(256) void gemm1_scatter(const float* __restrict__ x,
                                                     const u16* __restrict__ W1t,
                                                     const float* __restrict__ dinv,
                                                     u16* __restrict__ Hb, int M, int N,
                                                     int ngb,
                                                     const int* __restrict__ row,
                                                     const int* __restrict__ col,
                                                     int* __restrict__ bcur,
                                                     uint2* __restrict__ stage, int E) {
  __shared__ u16 ABsl[4][5120];  // 40KB: GEMM A/B double-buffer OR pass-A staging
  int b = blockIdx.x;
  if (b < ngb) {
    gemm_body<true>(x, W1t, dinv, Hb, M, N, b & 1, b >> 1,
                    *reinterpret_cast<u16(*)[2][5120]>(&ABsl[0]),
                    *reinterpret_cast<u16(*)[2][5120]>(&ABsl[2]));
  } else {
    uint2* pairs = (uint2*)ABsl;                       // 4096 pairs = 32KB
    int* hcnt = (int*)((char*)ABsl + 32768);           // [256]
    int* hscan = hcnt + 256;                           // [256]
    int* hbase = hscan + 256;                          // [256]
    int* lcur = hbase + 256;                           // [256]

    const int tid = threadIdx.x;
    const int blk = b - ngb;
    const int e0 = blk * CHUNK;

    hcnt[tid] = 0;
    __syncthreads();

    int ecol[16], erow[16];
#pragma unroll
    for (int j = 0; j < 16; ++j) {
      int e = e0 + j * 256 + tid;
      if (e < E) {
        ecol[j] = col[e];
        erow[j] = row[e];
        atomicAdd(&hcnt[ecol[j] >> 8], 1);
      } else {
        ecol[j] = -1;
      }
    }
    __syncthreads();

    hscan[tid] = hcnt[tid];
    __syncthreads();
#pragma unroll
    for (int off = 1; off < 256; off <<= 1) {
      int t = (tid >= off) ? hscan[tid - off] : 0;
      __syncthreads();
      hscan[tid] += t;
      __syncthreads();
    }

    lcur[tid] = 0;
    if (hcnt[tid] > 0) hbase[tid] = atomicAdd(&bcur[tid], hcnt[tid]);
    __syncthreads();

#pragma unroll
    for (int j = 0; j < 16; ++j) {
      if (ecol[j] >= 0) {
        int bk = ecol[j] >> 8;
        int p = atomicAdd(&lcur[bk], 1);
        pairs[(hscan[bk] - hcnt[bk]) + p] = make_uint2((unsigned)erow[j], (unsigned)ecol[j]);
      }
    }
    __syncthreads();

    int mtot = hscan[255];
    for (int s = tid; s < mtot; s += 256) {
      uint2 pr = pairs[s];
      int bk = (int)(pr.y >> 8);
      stage[hbase[bk] + (s - (hscan[bk] - hcnt[bk]))] = pr;
    }
  }
}

// pass B: per bucket counting-sort staged pairs to exact csr positions
__global__ __launch_bounds__(256) void csr_sort(const uint2* __restrict__ stage,
                                                const int* __restrict__ row_off,
                                                int* __restrict__ csr) {
  __shared__ int cur[256];
  __shared__ int outb[CAP_B];
  const int b = blockIdx.x;
  const int base_node = b << 8;
  const int nnodes = min(256, NN - base_node);
  const int tid = threadIdx.x;
  const int bstart = row_off[base_node];
  const int bend = row_off[min(base_node + 256, NN)];
  if (tid < nnodes) cur[tid] = row_off[base_node + tid] - bstart;
  __syncthreads();
  const int m = bend - bstart;
  for (int i = tid; i < m; i += 256) {
    uint2 pr = stage[bstart + i];
    int cl = min((int)pr.y - base_node, 255) & 255;  // defensive clamp
    int p = atomicAdd(&cur[cl], 1);
    if (p < CAP_B) outb[p] = (int)pr.x;
    else if (bstart + p < NE) csr[bstart + p] = (int)pr.x;  // bounded fallback
  }
  __syncthreads();
  const int mm = min(m, CAP_B);
  for (int i = tid; i < mm; i += 256) csr[bstart + i] = outb[i];
}

// ---------------- aggregation: XCD-sliced channel partition ----------------
// out[v][slice] = dinv[v] * (sum_{src in N(v)} Hs[src][slice] + Hs[v][slice]) + bias
//
// Feature dim split into NSL slices of 64 ch (128 B). slice = blockIdx % NSL:
// with round-robin block->XCD dispatch, each XCD gathers ONLY its slice of
// every row -> per-XCD gather footprint = rowbytes/NSL * NN (fits its 4MB L2),
// cutting the 8x cross-XCD L2-fill amplification (186 MB -> ~compulsory).
// Wave-per-node; lane = e*8 + c: 8 edges per gather instr (8 lanes x 16 B =
// 128 B/edge contiguous), 32 edge-slots per iter (4 gathers in flight), tail
// clamped to zero row at index NN; 3-step shfl_xor edge reduction.
// ALL gather indices pass through an unsigned min-clamp: a device fault from
// this kernel is impossible by construction.

template <int ROW_CH, int NSL, bool RELU_BF16>
__global__ __launch_bounds__(256) void agg_sliced(const u16* __restrict__ h,
                                                  const int* __restrict__ row_off,
                                                  const int* __restrict__ csr,
                                                  const float* __restrict__ dinv,
                                                  const float* __restrict__ bias,
                                                  void* __restrict__ outp, int n) {
  const int slice = blockIdx.x % NSL;
  const int v = (blockIdx.x / NSL) * 4 + (threadIdx.x >> 6);
  if (v >= n) return;
  const int lane = threadIdx.x & 63;
  const int c = lane & 7;    // channel octet within slice
  const int eg = lane >> 3;  // edge sub-slot (0..7)
  const int c0 = slice * 64 + c * 8;
  const int beg = row_off[v], end = row_off[v + 1];

  float a[8] = {};
  for (int base = beg; base < end; base += 32) {
    int p = base + (lane & 31);
    // clamp the csr read itself (p<NE always true here, but belt+braces)
    int idx = (p < end) ? csr[min(p, NE - 1)] : NN;
    idx = min((unsigned)idx, (unsigned)NN);  // zero row at NN absorbs tail
    unsigned s0 = min((unsigned)__shfl(idx, 0 + eg, 64), (unsigned)NN);
    unsigned s1 = min((unsigned)__shfl(idx, 8 + eg, 64), (unsigned)NN);
    unsigned s2 = min((unsigned)__shfl(idx, 16 + eg, 64), (unsigned)NN);
    unsigned s3 = min((unsigned)__shfl(idx, 24 + eg, 64), (unsigned)NN);
    ushort8 g0 = *(const ushort8*)&h[(size_t)s0 * ROW_CH + c0];
    ushort8 g1 = *(const ushort8*)&h[(size_t)s1 * ROW_CH + c0];
    ushort8 g2 = *(const ushort8*)&h[(size_t)s2 * ROW_CH + c0];
    ushort8 g3 = *(const ushort8*)&h[(size_t)s3 * ROW_CH + c0];
#pragma unroll
    for (int i = 0; i < 8; ++i) {
      a[i] += b2f((u16)g0[i]);
      a[i] += b2f((u16)g1[i]);
      a[i] += b2f((u16)g2[i]);
      a[i] += b2f((u16)g3[i]);
    }
  }
  // reduce over the 8 edge sub-slots (lane bits 3,4,5)
#pragma unroll
  for (int i = 0; i < 8; ++i) {
    a[i] += __shfl_xor(a[i], 8, 64);
    a[i] += __shfl_xor(a[i], 16, 64);
    a[i] += __shfl_xor(a[i], 32, 64);
  }
  if (eg == 0) {
    ushort8 hs = *(const ushort8*)&h[(size_t)v * ROW_CH + c0];
    float dv = dinv[v];
    float4 bv0 = *(const float4*)&bias[c0];
    float4 bv1 = *(const float4*)&bias[c0 + 4];
    float bb[8] = {bv0.x, bv0.y, bv0.z, bv0.w, bv1.x, bv1.y, bv1.z, bv1.w};
    if constexpr (RELU_BF16) {
      u16* out = (u16*)outp;
      ushort8 o;
#pragma unroll
      for (int i = 0; i < 8; ++i) {
        float r = fmaxf((a[i] + b2f((u16)hs[i])) * dv + bb[i], 0.f);
        o[i] = (short)f2b(r);
      }
      *(ushort8*)&out[(size_t)v * ROW_CH + c0] = o;
    } else {
      float* out = (float*)outp;
      float o[8];
#pragma unroll
      for (int i = 0; i < 8; ++i) o[i] = (a[i] + b2f((u16)hs[i])) * dv + bb[i];
      *(float4*)&out[(size_t)v * ROW_CH + c0] = make_float4(o[0], o[1], o[2], o[3]);
      *(float4*)&out[(size_t)v * ROW_CH + c0 + 4] = make_float4(o[4], o[5], o[6], o[7]);
    }
  }
}

// ---------------- launch ----------------

extern "C" void kernel_launch(void* const* d_in, const int* in_sizes, int n_in,
                              void* d_out, int out_size, void* d_ws, size_t ws_size,
                              hipStream_t stream) {
  const float* x = (const float*)d_in[0];
  const int* ei = (const int*)d_in[1];
  const float* W1 = (const float*)d_in[2];
  const float* b1 = (const float*)d_in[3];
  const float* W2 = (const float*)d_in[4];
  const float* b2 = (const float*)d_in[5];
  float* out = (float*)d_out;

  const int* row = ei;
  const int* col = ei + NE;

  const int NB = (NN + 255) / 256;  // 196

  // workspace layout — Hb and H3b carry one extra zero row at index NN
  u16* Hb = (u16*)d_ws;                       // [NN+1,256] bf16, pre-scaled by dinv[row]
  u16* H2b = Hb + (size_t)(NN + 1) * 256;     // [NN,256] bf16
  u16* H3b = H2b + (size_t)NN * 256;          // [NN+1,128] bf16, pre-scaled
  u16* W1t = H3b + (size_t)(NN + 1) * 128;    // [256,256] bf16
  u16* W2t = W1t + 256 * 256;                 // [128,256] bf16
  int* cnt = (int*)(W2t + 128 * 256);         // [NN]
  int* row_off = cnt + NN;                    // [NN+4] (padded)
  int* bcur = row_off + NN + 4;               // [256] per-bucket stage cursors
  float* dinv = (float*)(bcur + 256);         // [NN]
  int* bsum = (int*)(dinv + NN);              // [200]
  int* boff = bsum + 200;                     // [200]
  int* csr = boff + 200;                      // [NE+64] src only (64 ints slack)
  // stage overlays H3b: disjoint lifetimes (stage: [gemm1_scatter, csr_sort];
  // H3b data: [gemm2, agg128]); zero row untouched.
  uint2* stage = (uint2*)H3b;                 // [NE] (row,col) pairs

  convw_zero<<<256 + NB + 1, 256, 0, stream>>>(W1, W2, W1t, W2t, cnt,
                                               Hb + (size_t)NN * 256,
                                               H3b + (size_t)NN * 128, NB);
  hist_kernel<<<(NE + 255) / 256, 256, 0, stream>>>(col, cnt, NE);
  scan1_kernel<<<NB, 256, 0, stream>>>(cnt, bsum, NN);
  scan2_kernel<<<1, 256, 0, stream>>>(bsum, boff, row_off, NB, NN);
  scan3_kernel<<<NB, 256, 0, stream>>>(cnt, boff, row_off, bcur, dinv, NN);

  // fused: GEMM1 (Hb = dinv * (x@W1), bf16) concurrent with pass-A scatter
  {
    const int ngb = (HID_C / 128) * ((NN + 127) / 128);  // 782
    gemm1_scatter<<<ngb + NPA, 256, 0, stream>>>(x, W1t, dinv, Hb, NN, HID_C, ngb,
                                                 row, col, bcur, stage, NE);
  }
  csr_sort<<<NBUCK, 256, 0, stream>>>(stage, row_off, csr);

  // agg1: 4 slices x 64 ch, XCD-pinned via blockIdx % 4
  agg_sliced<256, 4, true><<<((NN + 3) / 4) * 4, 256, 0, stream>>>(
      Hb, row_off, csr, dinv, b1, H2b, NN);

  {
    dim3 grid(OUT_C / 128, (NN + 127) / 128);
    gemm_mfma<false><<<grid, 256, 0, stream>>>(H2b, W2t, dinv, H3b, NN, OUT_C);
  }

  // agg2: 2 slices x 64 ch
  agg_sliced<128, 2, false><<<((NN + 3) / 4) * 2, 256, 0, stream>>>(
      H3b, row_off, csr, dinv, b2, out, NN);
}

// Round 6
// 269.576 us; speedup vs baseline: 1.1329x; 1.1329x over previous
//
#include <hip/hip_runtime.h>

#define NN 50000
#define NE 800000
#define IN_C 256
#define HID_C 256
#define OUT_C 128

#define NBUCK 196   // ceil(NN/256) buckets of 256 nodes (by col)
#define CHUNK 4096  // edges per pass-A block
#define NPA 196     // ceil(NE/CHUNK)
#define CAP_B 5120  // pass-B LDS capacity (bucket mean 4096, sigma ~64)

typedef unsigned short u16;
typedef __attribute__((ext_vector_type(8))) short short8;
typedef __attribute__((ext_vector_type(8))) unsigned short ushort8;
typedef __attribute__((ext_vector_type(4))) float f32x4;

__device__ __forceinline__ u16 f2b(float f) {
  unsigned int u = __float_as_uint(f);
  return (u16)((u + 0x7FFFu + ((u >> 16) & 1u)) >> 16);  // RNE
}
__device__ __forceinline__ float b2f(u16 s) {
  return __uint_as_float(((unsigned int)s) << 16);
}

// ---------------- fused: weight convert+transpose, cnt zeroing, zero-row seed ----------------

__global__ __launch_bounds__(256) void convw_zero(const float* __restrict__ W1,
                                                  const float* __restrict__ W2,
                                                  u16* __restrict__ W1t,
                                                  u16* __restrict__ W2t,
                                                  int* __restrict__ cnt,
                                                  u16* __restrict__ Hbz,
                                                  u16* __restrict__ H3z,
                                                  int nzb) {
  int b = blockIdx.x;
  if (b < 256) {
    int id = b * 256 + threadIdx.x;
    if (id < 256 * 256) {
      int n = id >> 8, k = id & 255;
      W1t[id] = f2b(W1[k * 256 + n]);
    }
    if (id < 128 * 256) {
      int n = id >> 8, k = id & 255;
      W2t[id] = f2b(W2[k * 128 + n]);
    }
  } else if (b < 256 + nzb) {
    int i = (b - 256) * 256 + threadIdx.x;
    if (i < NN) cnt[i] = 0;
  } else {
    // zero rows used to absorb clamped tail gathers in the agg kernels
    if (threadIdx.x < 256) Hbz[threadIdx.x] = 0;
    if (threadIdx.x < 128) H3z[threadIdx.x] = 0;
  }
}

// ---------------- CSR build ----------------

__global__ __launch_bounds__(256) void hist_kernel(const int* __restrict__ col,
                                                   int* __restrict__ cnt, int E) {
  int e = blockIdx.x * blockDim.x + threadIdx.x;
  if (e < E) atomicAdd(&cnt[col[e]], 1);
}

__global__ __launch_bounds__(256) void scan1_kernel(const int* __restrict__ cnt,
                                                    int* __restrict__ bsum, int n) {
  __shared__ int ws[4];
  int i = blockIdx.x * 256 + threadIdx.x;
  int lane = threadIdx.x & 63, wid = threadIdx.x >> 6;
  int v = (i < n) ? cnt[i] : 0;
#pragma unroll
  for (int off = 32; off > 0; off >>= 1) v += __shfl_down(v, off, 64);
  if (lane == 0) ws[wid] = v;
  __syncthreads();
  if (threadIdx.x == 0) bsum[blockIdx.x] = ws[0] + ws[1] + ws[2] + ws[3];
}

__global__ __launch_bounds__(256) void scan2_kernel(const int* __restrict__ bsum,
                                                    int* __restrict__ boff,
                                                    int* __restrict__ row_off,
                                                    int nb, int n) {
  __shared__ int wsum[4], wpre[5];
  int lane = threadIdx.x & 63, wid = threadIdx.x >> 6;
  int v = (threadIdx.x < nb) ? bsum[threadIdx.x] : 0;
  int s = v;
#pragma unroll
  for (int off = 1; off < 64; off <<= 1) {
    int t = __shfl_up(s, off, 64);
    if (lane >= off) s += t;
  }
  if (lane == 63) wsum[wid] = s;
  __syncthreads();
  if (threadIdx.x == 0) {
    int acc = 0;
#pragma unroll
    for (int w = 0; w < 4; ++w) { wpre[w] = acc; acc += wsum[w]; }
    wpre[4] = acc;
  }
  __syncthreads();
  if (threadIdx.x < nb) boff[threadIdx.x] = wpre[wid] + (s - v);
  if (threadIdx.x == 0) row_off[n] = wpre[4];
}

// scan3 also seeds per-bucket stage cursors (bcur[b] = row_off[b*256])
__global__ __launch_bounds__(256) void scan3_kernel(const int* __restrict__ cnt,
                                                    const int* __restrict__ boff,
                                                    int* __restrict__ row_off,
                                                    int* __restrict__ bcur,
                                                    float* __restrict__ dinv, int n) {
  __shared__ int wsum[4], wpre[4];
  int i = blockIdx.x * 256 + threadIdx.x;
  int lane = threadIdx.x & 63, wid = threadIdx.x >> 6;
  int v = (i < n) ? cnt[i] : 0;
  int s = v;
#pragma unroll
  for (int off = 1; off < 64; off <<= 1) {
    int t = __shfl_up(s, off, 64);
    if (lane >= off) s += t;
  }
  if (lane == 63) wsum[wid] = s;
  __syncthreads();
  if (threadIdx.x == 0) {
    int acc = 0;
#pragma unroll
    for (int w = 0; w < 4; ++w) { wpre[w] = acc; acc += wsum[w]; }
  }
  __syncthreads();
  if (i < n) {
    int off = boff[blockIdx.x] + wpre[wid] + (s - v);
    row_off[i] = off;
    if ((i & 255) == 0) bcur[i >> 8] = off;
    dinv[i] = rsqrtf((float)(v + 1));
  }
}

// ---------------- MFMA GEMM body (shared by plain and fused kernels) ----------------

template <bool A_IS_F32>
__device__ __forceinline__ void gemm_body(const void* __restrict__ Ap,
                                          const u16* __restrict__ Bt,
                                          const float* __restrict__ dscale,
                                          u16* __restrict__ C, int M, int N,
                                          int bx, int by,
                                          u16 (&Asl)[2][5120], u16 (&Bsl)[2][5120]) {
  const int tid = threadIdx.x;
  const int row0 = by * 128;
  const int col0 = bx * 128;

  f32x4 acc[4][4] = {};

  const int seg = tid & 7;
  const int rb = tid >> 3;
  const int wave = tid >> 6, lane = tid & 63;
  const int wm = wave >> 1, wn = wave & 1;
  const int qr = lane & 15, quad = lane >> 4;

  float4 aF[4];
  ushort4 aU[4];
  ushort4 bR[4];

  auto load_tiles = [&](int k0) {
    if constexpr (A_IS_F32) {
      const float* A = (const float*)Ap;
#pragma unroll
      for (int i = 0; i < 4; ++i) {
        int gr = row0 + rb + i * 32;
        aF[i] = (gr < M) ? *(const float4*)&A[(size_t)gr * 256 + k0 + seg * 4]
                         : make_float4(0.f, 0.f, 0.f, 0.f);
      }
    } else {
      const u16* A = (const u16*)Ap;
#pragma unroll
      for (int i = 0; i < 4; ++i) {
        int gr = row0 + rb + i * 32;
        aU[i] = (gr < M) ? *(const ushort4*)&A[(size_t)gr * 256 + k0 + seg * 4]
                         : make_ushort4(0, 0, 0, 0);
      }
    }
#pragma unroll
    for (int i = 0; i < 4; ++i) {
      int n = rb + i * 32;
      bR[i] = *(const ushort4*)&Bt[(size_t)(col0 + n) * 256 + k0 + seg * 4];
    }
  };

  auto write_lds = [&](int buf) {
#pragma unroll
    for (int i = 0; i < 4; ++i) {
      int r = rb + i * 32;
      ushort4 u;
      if constexpr (A_IS_F32) {
        u.x = f2b(aF[i].x); u.y = f2b(aF[i].y);
        u.z = f2b(aF[i].z); u.w = f2b(aF[i].w);
      } else {
        u = aU[i];
      }
      *(ushort4*)&Asl[buf][r * 40 + seg * 4] = u;
      *(ushort4*)&Bsl[buf][r * 40 + seg * 4] = bR[i];
    }
  };

  load_tiles(0);
  write_lds(0);
  __syncthreads();

#pragma unroll
  for (int it = 0; it < 8; ++it) {
    const int cur = it & 1;
    if (it < 7) load_tiles((it + 1) * 32);

    short8 afr[4], bfr[4];
#pragma unroll
    for (int mt = 0; mt < 4; ++mt)
      afr[mt] = *(const short8*)&Asl[cur][(wm * 64 + mt * 16 + qr) * 40 + quad * 8];
#pragma unroll
    for (int nt = 0; nt < 4; ++nt)
      bfr[nt] = *(const short8*)&Bsl[cur][(wn * 64 + nt * 16 + qr) * 40 + quad * 8];
#pragma unroll
    for (int mt = 0; mt < 4; ++mt)
#pragma unroll
      for (int nt = 0; nt < 4; ++nt)
        acc[mt][nt] = __builtin_amdgcn_mfma_f32_16x16x32_bf16(afr[mt], bfr[nt], acc[mt][nt], 0, 0, 0);

    if (it < 7) {
      write_lds(1 - cur);
      __syncthreads();
    }
  }

#pragma unroll
  for (int mt = 0; mt < 4; ++mt) {
#pragma unroll
    for (int i = 0; i < 4; ++i) {
      int gr = row0 + wm * 64 + mt * 16 + quad * 4 + i;
      if (gr < M) {
        float sc = dscale[gr];
#pragma unroll
        for (int nt = 0; nt < 4; ++nt) {
          int gc = col0 + wn * 64 + nt * 16 + qr;
          C[(size_t)gr * N + gc] = f2b(acc[mt][nt][i] * sc);
        }
      }
    }
  }
}

// plain GEMM kernel (layer 2)
template <bool A_IS_F32>
__global__ __launch_bounds__(256) void gemm_mfma(const void* __restrict__ Ap,
                                                 const u16* __restrict__ Bt,
                                                 const float* __restrict__ dscale,
                                                 u16* __restrict__ C, int M, int N) {
  __shared__ u16 Asl[2][5120];
  __shared__ u16 Bsl[2][5120];
  gemm_body<A_IS_F32>(Ap, Bt, dscale, C, M, N, blockIdx.x, blockIdx.y, Asl, Bsl);
}

// fused: GEMM1 (blocks [0,ngb)) + pass-A bucket scatter (blocks [ngb, ngb+NPA))
__global__ __launch_bounds__(256) void gemm1_scatter(const float* __restrict__ x,
                                                     const u16* __restrict__ W1t,
                                                     const float* __restrict__ dinv,
                                                     u16* __restrict__ Hb, int M, int N,
                                                     int ngb,
                                                     const int* __restrict__ row,
                                                     const int* __restrict__ col,
                                                     int* __restrict__ bcur,
                                                     uint2* __restrict__ stage, int E) {
  __shared__ u16 ABsl[4][5120];  // 40KB: GEMM A/B double-buffer OR pass-A staging
  int b = blockIdx.x;
  if (b < ngb) {
    gemm_body<true>(x, W1t, dinv, Hb, M, N, b & 1, b >> 1,
                    *reinterpret_cast<u16(*)[2][5120]>(&ABsl[0]),
                    *reinterpret_cast<u16(*)[2][5120]>(&ABsl[2]));
  } else {
    uint2* pairs = (uint2*)ABsl;                       // 4096 pairs = 32KB
    int* hcnt = (int*)((char*)ABsl + 32768);           // [256]
    int* hscan = hcnt + 256;                           // [256]
    int* hbase = hscan + 256;                          // [256]
    int* lcur = hbase + 256;                           // [256]

    const int tid = threadIdx.x;
    const int blk = b - ngb;
    const int e0 = blk * CHUNK;

    hcnt[tid] = 0;
    __syncthreads();

    int ecol[16], erow[16];
#pragma unroll
    for (int j = 0; j < 16; ++j) {
      int e = e0 + j * 256 + tid;
      if (e < E) {
        ecol[j] = col[e];
        erow[j] = row[e];
        atomicAdd(&hcnt[ecol[j] >> 8], 1);
      } else {
        ecol[j] = -1;
      }
    }
    __syncthreads();

    hscan[tid] = hcnt[tid];
    __syncthreads();
#pragma unroll
    for (int off = 1; off < 256; off <<= 1) {
      int t = (tid >= off) ? hscan[tid - off] : 0;
      __syncthreads();
      hscan[tid] += t;
      __syncthreads();
    }

    lcur[tid] = 0;
    if (hcnt[tid] > 0) hbase[tid] = atomicAdd(&bcur[tid], hcnt[tid]);
    __syncthreads();

#pragma unroll
    for (int j = 0; j < 16; ++j) {
      if (ecol[j] >= 0) {
        int bk = ecol[j] >> 8;
        int p = atomicAdd(&lcur[bk], 1);
        pairs[(hscan[bk] - hcnt[bk]) + p] = make_uint2((unsigned)erow[j], (unsigned)ecol[j]);
      }
    }
    __syncthreads();

    int mtot = hscan[255];
    for (int s = tid; s < mtot; s += 256) {
      uint2 pr = pairs[s];
      int bk = (int)(pr.y >> 8);
      stage[hbase[bk] + (s - (hscan[bk] - hcnt[bk]))] = pr;
    }
  }
}

// pass B: per bucket counting-sort staged pairs to exact csr positions
__global__ __launch_bounds__(256) void csr_sort(const uint2* __restrict__ stage,
                                                const int* __restrict__ row_off,
                                                int* __restrict__ csr) {
  __shared__ int cur[256];
  __shared__ int outb[CAP_B];
  const int b = blockIdx.x;
  const int base_node = b << 8;
  const int nnodes = min(256, NN - base_node);
  const int tid = threadIdx.x;
  const int bstart = row_off[base_node];
  const int bend = row_off[min(base_node + 256, NN)];
  if (tid < nnodes) cur[tid] = row_off[base_node + tid] - bstart;
  __syncthreads();
  const int m = bend - bstart;
  for (int i = tid; i < m; i += 256) {
    uint2 pr = stage[bstart + i];
    int cl = min((int)pr.y - base_node, 255) & 255;  // defensive clamp
    int p = atomicAdd(&cur[cl], 1);
    if (p < CAP_B) outb[p] = (int)pr.x;
    else if (bstart + p < NE) csr[bstart + p] = (int)pr.x;  // bounded fallback
  }
  __syncthreads();
  const int mm = min(m, CAP_B);
  for (int i = tid; i < mm; i += 256) csr[bstart + i] = outb[i];
}

// ---------------- aggregation: XCD-sliced, 2 nodes/wave, 16-edge window ----------------
// out[v][slice] = dinv[v] * (sum_{src in N(v)} Hs[src][slice] + Hs[v][slice]) + bias
//
// Slicing (kept from r5 — proven FETCH 186->109 MB): slice = blockIdx % NSL
// rides round-robin block->XCD dispatch; each XCD gathers only its 64-ch slice.
// VALU fixes (r5 was 83% VALU-bound): 2 nodes/wave (halves wave count to 100K,
// amortizes prologue/reduce/store), 16-edge window per node (halves zero-row
// waste at mean deg 16; the shorter node's extra iterations are exec-masked ->
// no memory traffic), 2-step reduce (eg in lane bits 3-4), clamps removed
// (csr contents in [0,NN) by construction, verified r5; only tail ternary kept).
// Lane map: nd=lane>>5 (node), l5=lane&31, eg=l5>>3 (4 edge slots), c=l5&7
// (8 ch octets = 64 ch). Per iter: 4 gathers x 8 edges x 128 B, 16 edges/node.

template <int ROW_CH, int NSL, bool RELU_BF16>
__global__ __launch_bounds__(256) void agg_sliced2(const u16* __restrict__ h,
                                                   const int* __restrict__ row_off,
                                                   const int* __restrict__ csr,
                                                   const float* __restrict__ dinv,
                                                   const float* __restrict__ bias,
                                                   void* __restrict__ outp, int n) {
  constexpr int SH = (ROW_CH == 256) ? 8 : 7;
  const int slice = blockIdx.x % NSL;
  const int wave = threadIdx.x >> 6;
  const int lane = threadIdx.x & 63;
  const int nd = lane >> 5;
  const int l5 = lane & 31;
  const int eg = l5 >> 3;
  const int c0 = slice * 64 + (l5 & 7) * 8;
  const int v = (blockIdx.x / NSL) * 8 + wave * 2 + nd;  // NN % 8 == 0 -> v < NN
  const int beg = row_off[v], end = row_off[v + 1];
  const int srcl = (nd << 5) + eg;

  float a[8] = {};
  for (int base = beg; base < end; base += 16) {
    int p = base + (l5 & 15);
    int idx = (p < end) ? csr[p] : NN;  // tail -> zero row at NN
    unsigned s0 = (unsigned)__shfl(idx, srcl, 64);
    unsigned s1 = (unsigned)__shfl(idx, srcl + 4, 64);
    unsigned s2 = (unsigned)__shfl(idx, srcl + 8, 64);
    unsigned s3 = (unsigned)__shfl(idx, srcl + 12, 64);
    ushort8 g0 = *(const ushort8*)&h[(s0 << SH) + c0];
    ushort8 g1 = *(const ushort8*)&h[(s1 << SH) + c0];
    ushort8 g2 = *(const ushort8*)&h[(s2 << SH) + c0];
    ushort8 g3 = *(const ushort8*)&h[(s3 << SH) + c0];
#pragma unroll
    for (int i = 0; i < 8; ++i) {
      a[i] += b2f((u16)g0[i]);
      a[i] += b2f((u16)g1[i]);
      a[i] += b2f((u16)g2[i]);
      a[i] += b2f((u16)g3[i]);
    }
  }
  // reduce over the 4 edge sub-slots (lane bits 3,4) — stays within node half
#pragma unroll
  for (int i = 0; i < 8; ++i) {
    a[i] += __shfl_xor(a[i], 8, 64);
    a[i] += __shfl_xor(a[i], 16, 64);
  }
  if (eg == 0) {
    ushort8 hs = *(const ushort8*)&h[((unsigned)v << SH) + c0];
    float dv = dinv[v];
    float4 bv0 = *(const float4*)&bias[c0];
    float4 bv1 = *(const float4*)&bias[c0 + 4];
    float bb[8] = {bv0.x, bv0.y, bv0.z, bv0.w, bv1.x, bv1.y, bv1.z, bv1.w};
    if constexpr (RELU_BF16) {
      u16* out = (u16*)outp;
      ushort8 o;
#pragma unroll
      for (int i = 0; i < 8; ++i) {
        float r = fmaxf((a[i] + b2f((u16)hs[i])) * dv + bb[i], 0.f);
        o[i] = (short)f2b(r);
      }
      *(ushort8*)&out[((size_t)v << SH) + c0] = o;
    } else {
      float* out = (float*)outp;
      float o[8];
#pragma unroll
      for (int i = 0; i < 8; ++i) o[i] = (a[i] + b2f((u16)hs[i])) * dv + bb[i];
      *(float4*)&out[((size_t)v << SH) + c0] = make_float4(o[0], o[1], o[2], o[3]);
      *(float4*)&out[((size_t)v << SH) + c0 + 4] = make_float4(o[4], o[5], o[6], o[7]);
    }
  }
}

// ---------------- launch ----------------

extern "C" void kernel_launch(void* const* d_in, const int* in_sizes, int n_in,
                              void* d_out, int out_size, void* d_ws, size_t ws_size,
                              hipStream_t stream) {
  const float* x = (const float*)d_in[0];
  const int* ei = (const int*)d_in[1];
  const float* W1 = (const float*)d_in[2];
  const float* b1 = (const float*)d_in[3];
  const float* W2 = (const float*)d_in[4];
  const float* b2 = (const float*)d_in[5];
  float* out = (float*)d_out;

  const int* row = ei;
  const int* col = ei + NE;

  const int NB = (NN + 255) / 256;  // 196

  // workspace layout — Hb and H3b carry one extra zero row at index NN
  u16* Hb = (u16*)d_ws;                       // [NN+1,256] bf16, pre-scaled by dinv[row]
  u16* H2b = Hb + (size_t)(NN + 1) * 256;     // [NN,256] bf16
  u16* H3b = H2b + (size_t)NN * 256;          // [NN+1,128] bf16, pre-scaled
  u16* W1t = H3b + (size_t)(NN + 1) * 128;    // [256,256] bf16
  u16* W2t = W1t + 256 * 256;                 // [128,256] bf16
  int* cnt = (int*)(W2t + 128 * 256);         // [NN]
  int* row_off = cnt + NN;                    // [NN+4] (padded)
  int* bcur = row_off + NN + 4;               // [256] per-bucket stage cursors
  float* dinv = (float*)(bcur + 256);         // [NN]
  int* bsum = (int*)(dinv + NN);              // [200]
  int* boff = bsum + 200;                     // [200]
  int* csr = boff + 200;                      // [NE+64] src only (64 ints slack)
  // stage overlays H3b: disjoint lifetimes (stage: [gemm1_scatter, csr_sort];
  // H3b data: [gemm2, agg128]); zero row untouched.
  uint2* stage = (uint2*)H3b;                 // [NE] (row,col) pairs

  convw_zero<<<256 + NB + 1, 256, 0, stream>>>(W1, W2, W1t, W2t, cnt,
                                               Hb + (size_t)NN * 256,
                                               H3b + (size_t)NN * 128, NB);
  hist_kernel<<<(NE + 255) / 256, 256, 0, stream>>>(col, cnt, NE);
  scan1_kernel<<<NB, 256, 0, stream>>>(cnt, bsum, NN);
  scan2_kernel<<<1, 256, 0, stream>>>(bsum, boff, row_off, NB, NN);
  scan3_kernel<<<NB, 256, 0, stream>>>(cnt, boff, row_off, bcur, dinv, NN);

  // fused: GEMM1 (Hb = dinv * (x@W1), bf16) concurrent with pass-A scatter
  {
    const int ngb = (HID_C / 128) * ((NN + 127) / 128);  // 782
    gemm1_scatter<<<ngb + NPA, 256, 0, stream>>>(x, W1t, dinv, Hb, NN, HID_C, ngb,
                                                 row, col, bcur, stage, NE);
  }
  csr_sort<<<NBUCK, 256, 0, stream>>>(stage, row_off, csr);

  // agg1: 4 slices x 64 ch, XCD-pinned via blockIdx % 4; 8 nodes/block
  agg_sliced2<256, 4, true><<<(NN / 8) * 4, 256, 0, stream>>>(
      Hb, row_off, csr, dinv, b1, H2b, NN);

  {
    dim3 grid(OUT_C / 128, (NN + 127) / 128);
    gemm_mfma<false><<<grid, 256, 0, stream>>>(H2b, W2t, dinv, H3b, NN, OUT_C);
  }

  // agg2: 2 slices x 64 ch; 8 nodes/block
  agg_sliced2<128, 2, false><<<(NN / 8) * 2, 256, 0, stream>>>(
      H3b, row_off, csr, dinv, b2, out, NN);
}